// Round 8
// baseline (95.311 us; speedup 1.0000x reference)
//
#include <hip/hip_runtime.h>
#include <math.h>

#define BB 4
#define CC 256
#define NN 4096
#define KK 32
#define DD 256
#define GG 8    // C/K
#define NEs 64  // n-slices of 64 (k_pm1 tiles, k_dist tiles)
#define NE8 8   // n-eighths in k_xq

__device__ __forceinline__ float wredsum(float v) {
#pragma unroll
  for (int o = 32; o > 0; o >>= 1) v += __shfl_xor(v, o, 64);
  return v;
}

// Kernel 1: fused phi (grouped conv + exp, LDS-only, recomputed per c-half)
// + m1 half-partials. grid = B*64slice*2half = 512 blocks, block 512.
// m1e layout [(e,h)][b][k][c] (each block fills its 128-c half of the row);
// SpE[e][b][k] written by h==0 blocks.
__global__ __launch_bounds__(512) void k_pm1(const float* __restrict__ x,
                                             const float* __restrict__ wphi,
                                             float* __restrict__ m1e,
                                             float* __restrict__ SpE) {
  const int b = blockIdx.x >> 7;
  const int e = (blockIdx.x >> 1) & 63;
  const int h = blockIdx.x & 1;
  const int n0 = e * 64;
  const int c0 = h * 128;
  const int tid = threadIdx.x;
  __shared__ float phis[32 * 65];  // phi[k][n_local], pad 65
  __shared__ float tr[128 * 33];   // transpose buffer
  // --- conv + exp into LDS (all 32 k, this block's 64 n) ---
  {
    const int kk = tid >> 4;  // 0..31
    const int m = tid & 15;   // 4 n each
    const float* xb = x + (size_t)(b * CC + kk * GG) * NN + n0 + m * 4;
    float w[GG];
#pragma unroll
    for (int j = 0; j < GG; ++j) w[j] = wphi[kk * GG + j];
    float4 s = make_float4(0.f, 0.f, 0.f, 0.f);
#pragma unroll
    for (int j = 0; j < GG; ++j) {
      const float4 xv = *reinterpret_cast<const float4*>(xb + (size_t)j * NN);
      s.x = fmaf(xv.x, w[j], s.x);
      s.y = fmaf(xv.y, w[j], s.y);
      s.z = fmaf(xv.z, w[j], s.z);
      s.w = fmaf(xv.w, w[j], s.w);
    }
    float* pr = phis + kk * 65 + m * 4;
    pr[0] = __expf(s.x);
    pr[1] = __expf(s.y);
    pr[2] = __expf(s.z);
    pr[3] = __expf(s.w);
  }
  __syncthreads();
  if (h == 0 && tid < 32) {
    float s = 0.f;
#pragma unroll 8
    for (int n = 0; n < 64; ++n) s += phis[tid * 65 + n];
    SpE[((size_t)e * BB + b) * KK + tid] = s;
  }
  // --- m1: thread (k = tid&31, ct = tid>>5 -> 8 c's of this half) ---
  const int k = tid & 31;
  const int ct = tid >> 5;  // 0..15
  float acc[8] = {0.f, 0.f, 0.f, 0.f, 0.f, 0.f, 0.f, 0.f};
  const float* xm = x + (size_t)(b * CC + c0 + ct * 8) * NN + n0;
#pragma unroll
  for (int sub = 0; sub < 4; ++sub) {
    float ph[16];
#pragma unroll
    for (int i = 0; i < 16; ++i) ph[i] = phis[k * 65 + sub * 16 + i];
#pragma unroll
    for (int c = 0; c < 8; ++c) {
      const float* xr = xm + (size_t)c * NN + sub * 16;
#pragma unroll
      for (int n4 = 0; n4 < 4; ++n4) {
        const float4 xv = *reinterpret_cast<const float4*>(xr + n4 * 4);
        acc[c] = fmaf(xv.x, ph[n4 * 4 + 0], acc[c]);
        acc[c] = fmaf(xv.y, ph[n4 * 4 + 1], acc[c]);
        acc[c] = fmaf(xv.z, ph[n4 * 4 + 2], acc[c]);
        acc[c] = fmaf(xv.w, ph[n4 * 4 + 3], acc[c]);
      }
    }
  }
#pragma unroll
  for (int i = 0; i < 8; ++i) tr[(ct * 8 + i) * 33 + k] = acc[i];
  __syncthreads();
  float* mb = m1e + ((size_t)(e * 2 + h) * BB + b) * KK * CC;
#pragma unroll
  for (int o = 0; o < 8; ++o) {
    const int idx = o * 512 + tid;
    const int c2 = idx & 127, k2 = idx >> 7;
    mb[(size_t)k2 * CC + c0 + c2] = tr[c2 * 33 + k2];
  }
}

// Kernel 2: S = sum SpE; M1 = (sum_e m1e)/S; code = w_theta @ M1 normalized
// over d; emit code, bc2 = 2*s2*code, s2, t3. grid = B*K, block 256.
__global__ __launch_bounds__(256) void k_code(const float* __restrict__ m1e,
                                              const float* __restrict__ SpE,
                                              const float* __restrict__ wth,
                                              const float* __restrict__ scale,
                                              float* __restrict__ code,
                                              float* __restrict__ bc2,
                                              float* __restrict__ s2g,
                                              float* __restrict__ t3) {
  const int b = blockIdx.x >> 5;
  const int k = blockIdx.x & 31;
  const int d = threadIdx.x;
  __shared__ __align__(16) float m1s[CC];
  __shared__ float rb[4];
  float sp = (d < NEs) ? SpE[((size_t)d * BB + b) * KK + k] : 0.f;
  sp = wredsum(sp);
  if ((d & 63) == 0) rb[d >> 6] = sp;
  __syncthreads();
  const float invS = 1.f / (rb[0] + rb[1] + rb[2] + rb[3]);
  const int hsel = d >> 7;
  float m = 0.f;
  for (int e = 0; e < NEs; ++e)
    m += m1e[(((size_t)(e * 2 + hsel) * BB + b) * KK + k) * CC + d];
  m1s[d] = m * invS;
  __syncthreads();
  float cd = 0.f;
  const float* wt = wth + (size_t)d * CC;
#pragma unroll 4
  for (int c = 0; c < CC; c += 4) {
    const float4 w4 = *reinterpret_cast<const float4*>(wt + c);
    const float4 m4 = *reinterpret_cast<const float4*>(&m1s[c]);
    cd = fmaf(w4.x, m4.x, cd);
    cd = fmaf(w4.y, m4.y, cd);
    cd = fmaf(w4.z, m4.z, cd);
    cd = fmaf(w4.w, m4.w, cd);
  }
  float ss = wredsum(cd * cd);
  __syncthreads();
  if ((d & 63) == 0) rb[d >> 6] = ss;
  __syncthreads();
  const float nrm = sqrtf(rb[0] + rb[1] + rb[2] + rb[3]);
  const float inv = 1.f / fmaxf(nrm, 1e-12f);
  cd *= inv;
  const float sc = scale[(size_t)d * KK + k];
  const float s2 = sc * sc;
  code[((size_t)b * DD + d) * KK + k] = cd;
  bc2[((size_t)b * DD + d) * KK + k] = 2.f * s2 * cd;
  if (b == 0) s2g[(size_t)d * KK + k] = s2;
  float tt = wredsum(s2 * cd * cd);
  __syncthreads();
  if ((d & 63) == 0) rb[d >> 6] = tt;
  __syncthreads();
  if (d == 0) t3[b * KK + k] = rb[0] + rb[1] + rb[2] + rb[3];
}

// Kernel 3: dist + softmax(k) -> Q (d_out) + qpart.
// grid = B*64 (64-n tiles), block 512 (8 waves = 8 d-stripes of 32).
// Wave-uniform s2/bc2 rows -> SGPR scalar broadcasts; lanes = 64 n.
__global__ __launch_bounds__(512) void k_dist(const float* __restrict__ x,
                                              const float* __restrict__ s2g,
                                              const float* __restrict__ bc2,
                                              const float* __restrict__ t3,
                                              float* __restrict__ qout,
                                              float* __restrict__ qpart) {
  const int b = blockIdx.x >> 6;
  const int tile = blockIdx.x & 63;
  const int n0 = tile * 64;
  const int tid = threadIdx.x;
  const int lane = tid & 63;
  const int wid = __builtin_amdgcn_readfirstlane(tid >> 6);  // 0..7
  const int d0 = wid * 32;
  __shared__ float lds[4 * 64 * 33];
  __shared__ float smax[64 * 9];
  __shared__ float ssum[64 * 9];
  float accA[32], accB[32];
#pragma unroll
  for (int k = 0; k < 32; ++k) { accA[k] = 0.f; accB[k] = 0.f; }
  const float* xb = x + ((size_t)b * CC + d0) * NN + n0 + lane;
  const float* s2b = s2g + (size_t)d0 * KK;
  const float* bcb = bc2 + ((size_t)b * DD + d0) * KK;
#pragma unroll 2
  for (int dd = 0; dd < 32; ++dd) {
    const float xv = xb[(size_t)dd * NN];
    const float x2 = xv * xv;
    const float* s2r = s2b + dd * KK;
    const float* bcr = bcb + dd * KK;
#pragma unroll
    for (int k = 0; k < 32; ++k) {
      accA[k] = fmaf(x2, s2r[k], accA[k]);
      accB[k] = fmaf(xv, bcr[k], accB[k]);
    }
  }
  if (wid >= 4) {
    float* Lp = lds + ((size_t)((wid - 4) * 64 + lane)) * 33;
#pragma unroll
    for (int k = 0; k < 32; ++k) Lp[k] = accA[k] - accB[k];
  }
  __syncthreads();
  if (wid < 4) {
    float* Lp = lds + ((size_t)(wid * 64 + lane)) * 33;
#pragma unroll
    for (int k = 0; k < 32; ++k) Lp[k] += accA[k] - accB[k];
  }
  __syncthreads();
  const int n = lane;
  const int kq = wid;
  float vals[4];
#pragma unroll
  for (int j = 0; j < 4; ++j) {
    const int k = kq * 4 + j;
    float s = 0.f;
#pragma unroll
    for (int g = 0; g < 4; ++g) s += lds[((size_t)(g * 64 + n)) * 33 + k];
    vals[j] = -0.5f * (s + t3[b * KK + k]);
  }
  float m4 = fmaxf(fmaxf(vals[0], vals[1]), fmaxf(vals[2], vals[3]));
  smax[n * 9 + kq] = m4;
  __syncthreads();
  float m = smax[n * 9 + 0];
#pragma unroll
  for (int g = 1; g < 8; ++g) m = fmaxf(m, smax[n * 9 + g]);
  float e[4];
  float ps = 0.f;
#pragma unroll
  for (int j = 0; j < 4; ++j) {
    e[j] = __expf(vals[j] - m);
    ps += e[j];
  }
  ssum[n * 9 + kq] = ps;
  __syncthreads();
  float tot = 0.f;
#pragma unroll
  for (int g = 0; g < 8; ++g) tot += ssum[n * 9 + g];
  const float inv = 1.f / tot;
  float4 q4;
  q4.x = e[0] * inv; q4.y = e[1] * inv;
  q4.z = e[2] * inv; q4.w = e[3] * inv;
  *reinterpret_cast<float4*>(qout + ((size_t)b * NN + n0 + n) * KK + kq * 4) =
      q4;
  float qs[4] = {q4.x, q4.y, q4.z, q4.w};
#pragma unroll
  for (int j = 0; j < 4; ++j) {
    const float v = wredsum(qs[j]);
    if (n == 0) qpart[((size_t)b * KK + kq * 4 + j) * NEs + tile] = v;
  }
}

// Kernel 4: znq8[e][b][k][c] = sum_{n in eighth} x[c,n] * Q[n,k],
// Q LDS-staged in 256-n chunks (coalesced loads, conflict-free reads).
// grid = B*32ct*8e = 1024, block 256.
__global__ __launch_bounds__(256) void k_xq(const float* __restrict__ x,
                                            const float* __restrict__ q,
                                            float* __restrict__ znq8) {
  const int e = blockIdx.x & 7;
  const int ct = (blockIdx.x >> 3) & 31;
  const int b = blockIdx.x >> 8;
  const int tid = threadIdx.x;
  __shared__ float qs[256 * 33];  // Q[n_local][k], pad 33
  const int k = tid & 31;
  const int g = tid >> 5;  // 8 groups of 32 n
  float acc[8] = {0.f, 0.f, 0.f, 0.f, 0.f, 0.f, 0.f, 0.f};
  const float* xb = x + (size_t)(b * CC + ct * 8) * NN;
#pragma unroll
  for (int ch = 0; ch < 2; ++ch) {
    const int n0 = e * 512 + ch * 256;
    const float* qr = q + ((size_t)b * NN + n0 + tid) * KK;
#pragma unroll
    for (int j = 0; j < 8; ++j) {
      const float4 qv = *reinterpret_cast<const float4*>(qr + j * 4);
      float* dst = qs + tid * 33 + j * 4;
      dst[0] = qv.x; dst[1] = qv.y; dst[2] = qv.z; dst[3] = qv.w;
    }
    __syncthreads();
#pragma unroll
    for (int i = 0; i < 8; ++i) {
      const int nl = g * 32 + i * 4;
      const float p0 = qs[(nl + 0) * 33 + k];
      const float p1 = qs[(nl + 1) * 33 + k];
      const float p2 = qs[(nl + 2) * 33 + k];
      const float p3 = qs[(nl + 3) * 33 + k];
#pragma unroll
      for (int c = 0; c < 8; ++c) {
        const float4 xv =
            *reinterpret_cast<const float4*>(xb + (size_t)c * NN + n0 + nl);
        acc[c] = fmaf(xv.x, p0, acc[c]);
        acc[c] = fmaf(xv.y, p1, acc[c]);
        acc[c] = fmaf(xv.z, p2, acc[c]);
        acc[c] = fmaf(xv.w, p3, acc[c]);
      }
    }
    __syncthreads();
  }
  // cross-g reduce (reuse qs)
#pragma unroll
  for (int c = 0; c < 8; ++c) qs[(g * 8 + c) * 33 + k] = acc[c];
  __syncthreads();
  const int c2 = tid & 7, k2 = tid >> 3;
  float s = 0.f;
#pragma unroll
  for (int gg = 0; gg < 8; ++gg) s += qs[(gg * 8 + c2) * 33 + k2];
  znq8[((size_t)(e * BB + b) * KK + k2) * CC + ct * 8 + c2] = s;
}

// Kernel 5: Qsum reduce + Z = scale*(Znum/Qsum - code), d-normalized.
// grid = B*K, block 256.
__global__ __launch_bounds__(256) void k_z(const float* __restrict__ znq8,
                                           const float* __restrict__ code,
                                           const float* __restrict__ scale,
                                           const float* __restrict__ qpart,
                                           float* __restrict__ zout) {
  const int b = blockIdx.x >> 5;
  const int k = blockIdx.x & 31;
  const int d = threadIdx.x;
  __shared__ float rb[4];
  float qp = (d < NEs) ? qpart[((size_t)b * KK + k) * NEs + d] : 0.f;
  qp = wredsum(qp);
  if ((d & 63) == 0) rb[d >> 6] = qp;
  __syncthreads();
  const float qs = rb[0] + rb[1] + rb[2] + rb[3];
  float zn = 0.f;
#pragma unroll
  for (int e = 0; e < NE8; ++e)
    zn += znq8[((size_t)(e * BB + b) * KK + k) * CC + d];
  const float cd = code[((size_t)b * DD + d) * KK + k];
  const float z_ = scale[(size_t)d * KK + k] * (zn / qs - cd);
  float ss = wredsum(z_ * z_);
  __syncthreads();
  if ((d & 63) == 0) rb[d >> 6] = ss;
  __syncthreads();
  const float rn = 1.f / sqrtf(rb[0] + rb[1] + rb[2] + rb[3]);
  zout[((size_t)b * DD + d) * KK + k] = z_ * rn;
}

extern "C" void kernel_launch(void* const* d_in, const int* in_sizes, int n_in,
                              void* d_out, int out_size, void* d_ws,
                              size_t ws_size, hipStream_t stream) {
  const float* x = (const float*)d_in[0];
  const float* wth = (const float*)d_in[1];
  const float* wphi = (const float*)d_in[2];
  const float* scale = (const float*)d_in[3];
  float* out = (float*)d_out;
  float* zout = out;                         // B*D*K = 32768
  float* qout = out + (size_t)BB * DD * KK;  // B*N*K = 524288
  float* ws = (float*)d_ws;
  float* SpE = ws;                                      // 64*B*K      = 8192
  float* m1e = SpE + (size_t)NEs * BB * KK;             // 128*B*K*C   = 4194304
  float* code = m1e + (size_t)NEs * 2 * BB * KK * CC;   // B*D*K       = 32768
  float* bc2 = code + (size_t)BB * DD * KK;             // B*D*K       = 32768
  float* s2g = bc2 + (size_t)BB * DD * KK;              // D*K         = 8192
  float* t3 = s2g + (size_t)DD * KK;                    // B*K         = 128
  float* qpart = t3 + BB * KK;                          // B*K*64      = 8192
  float* znq8 = qpart + (size_t)BB * KK * NEs;          // 8*B*K*C     = 262144

  k_pm1<<<BB * NEs * 2, 512, 0, stream>>>(x, wphi, m1e, SpE);
  k_code<<<BB * KK, 256, 0, stream>>>(m1e, SpE, wth, scale, code, bc2, s2g, t3);
  k_dist<<<BB * NEs, 512, 0, stream>>>(x, s2g, bc2, t3, qout, qpart);
  k_xq<<<BB * 32 * NE8, 256, 0, stream>>>(x, qout, znq8);
  k_z<<<BB * KK, 256, 0, stream>>>(znq8, code, scale, qpart, zout);
}